// Round 8
// baseline (325.193 us; speedup 1.0000x reference)
//
#include <hip/hip_runtime.h>

// CharBiLSTMEmbedder: N=32768 words, T=20, E=H=50, V=200, out [N,100] fp32.
//
// Round-8: (a) 4 waves/SIMD done right: 1024-thr blocks with
// amdgpu_waves_per_eu(4,4) -> VGPR target exactly 128 (R7's launch_bounds(1024,4)
// let the allocator collapse to 64 VGPRs -> 478 MB scratch spills).
// (b) sort moved INTO k_lstm: each block counting-sorts its 256 words (one dir)
// in LDS; sorted 16-word groups assigned to waves via a magic-square table so
// per-SIMD load is balanced under either wave->SIMD mapping. k_scat gone.
// (c) Wa self-staged from Whh. Net: 2 dispatches (k_prep G-only, k_lstm).

#define TT    20
#define HH    50
#define VV    200
#define TILES 13        // 13*16 = 208 rows >= 200
#define GSTR  212       // G LDS row stride in shorts (53 units * 4 gates)
#define GSH   (VV * GSTR)        // 42400 shorts per dir
#define WSH   (TILES * 16 * 64)  // 13312 shorts per dir
#define NW    32768

typedef __attribute__((ext_vector_type(8))) short bf16x8;
typedef __attribute__((ext_vector_type(4))) short s16x4;
typedef __attribute__((ext_vector_type(4))) float f32x4;

__device__ __forceinline__ float frcp(float x) { return __builtin_amdgcn_rcpf(x); }
__device__ __forceinline__ float fsig(float x) { return frcp(1.0f + __expf(-x)); }
__device__ __forceinline__ float ftanhf(float x) { return 1.0f - 2.0f * frcp(1.0f + __expf(2.0f * x)); }

__device__ __forceinline__ short f2bf(float x) {  // RNE fp32 -> bf16
    unsigned b = __builtin_bit_cast(unsigned, x);
    unsigned r = (b + 0x7FFFu + ((b >> 16) & 1u)) >> 16;
    return (short)r;
}
__device__ __forceinline__ float bf2f(short s) {
    return __builtin_bit_cast(float, ((unsigned)(unsigned short)s) << 16);
}

// Gimg[d][v*GSTR+u*4+g] = bf16(emb'[v].W_ih[g*50+u] + b_ih + b_hh)
__global__ void k_prep(const float* __restrict__ emb,
                       const float* __restrict__ Wih_f, const float* __restrict__ bih_f,
                       const float* __restrict__ bhh_f,
                       const float* __restrict__ Wih_b, const float* __restrict__ bih_b,
                       const float* __restrict__ bhh_b,
                       short* __restrict__ Gimg) {
    int idx = blockIdx.x * 256 + threadIdx.x;
    if (idx >= 2 * GSH) return;
    int d = idx / GSH;
    int rem = idx % GSH;
    int v = rem / GSTR;
    int u = (rem % GSTR) >> 2;
    int g = idx & 3;
    if (u >= HH) { Gimg[idx] = 0; return; }
    int r = g * HH + u;
    const float* Wih = d ? Wih_b : Wih_f;
    const float* bih = d ? bih_b : bih_f;
    const float* bhh = d ? bhh_b : bhh_f;
    float s = bih[r] + bhh[r];
    if (v != 0) {  // PAD row of emb is zero
        #pragma unroll 10
        for (int e = 0; e < HH; ++e) s = fmaf(emb[v * HH + e], Wih[r * HH + e], s);
    }
    Gimg[idx] = f2bf(s);
}

__global__ void __launch_bounds__(1024)
__attribute__((amdgpu_waves_per_eu(4, 4)))
k_lstm(const int* __restrict__ chars, const int* __restrict__ lens,
       const short* __restrict__ Gimg,
       const float* __restrict__ Whh_f, const float* __restrict__ Whh_b,
       float* __restrict__ out) {
    __shared__ __align__(16) short Wa[WSH];        // 26624 B
    __shared__ __align__(16) short Gl[GSH];        // 84800 B
    __shared__ __align__(16) short hs[16][1024];   // 32768 B per-wave h
    __shared__ unsigned char cs[16][320];          //  5120 B per-wave chars
    __shared__ int sw[256];                        // sorted word ids
    __shared__ int hist[21], start[21];

    int gb   = blockIdx.x;         // 0..255
    int d    = gb & 1;
    int wb   = (gb >> 1) * 256;    // block's first word
    int tid  = threadIdx.x;        // 0..1023
    int lane = tid & 63;
    int wv   = __builtin_amdgcn_readfirstlane(tid >> 6);   // 0..15
    int quad = lane >> 4;
    int n    = lane & 15;
    int x7   = n & 7;

    // ---- stage Wa from Whh (bf16, MFMA A-layout, k-swizzled); coalesced ----
    {
        const float* Whh = d ? Whh_b : Whh_f;
        for (int e = tid; e < WSH; e += 1024) {
            int t = e >> 10, m = (e >> 6) & 15, k = e & 63;
            int u = 4 * t + (m >> 2), g = m & 3;
            float val = (k < HH && u < HH) ? Whh[(g * HH + u) * HH + k] : 0.0f;
            int ksw = (k & 7) | (((k >> 3) ^ (m & 7)) << 3);
            Wa[(e & ~63) + ksw] = f2bf(val);
        }
    }
    // ---- copy G image (coalesced int4) ----
    {
        const int4* src = (const int4*)(Gimg + d * GSH);
        int4* dst = (int4*)Gl;
        for (int i = tid; i < GSH / 8; i += 1024) dst[i] = src[i];
    }
    // ---- zero h buffers ----
    {
        int4 z = {0, 0, 0, 0};
        int4* hz = (int4*)&hs[0][0];
        for (int i = tid; i < 16 * 1024 / 8; i += 1024) hz[i] = z;
    }
    // ---- in-block counting sort of 256 word lengths (descending) ----
    if (tid < 21) hist[tid] = 0;
    __syncthreads();
    int Lw = 0;
    if (tid < 256) {
        Lw = lens[wb + tid];
        atomicAdd(&hist[Lw], 1);
    }
    __syncthreads();
    if (tid < 21) {   // start[L] = count of longer words (descending buckets)
        int s = 0;
        for (int l = tid + 1; l < 21; ++l) s += hist[l];
        start[tid] = s;
    }
    __syncthreads();
    if (tid < 256) {
        int pos = atomicAdd(&start[Lw], 1);
        sw[pos] = wb + tid;
    }
    __syncthreads();

    // magic-square group table: per-SIMD sums equal under both w%4 and w/4
    // wave->SIMD mappings (rows and cols of the 4x4 all sum to 30)
    const int gtab[16] = {0, 14, 13, 3, 11, 5, 6, 8, 7, 9, 10, 4, 12, 2, 1, 15};
    int slotbase = gtab[wv] * 16;

    {   // wave's 16 words x 20 chars -> u8 LDS
        for (int i = lane; i < 16 * TT; i += 64) {
            int w = sw[slotbase + i / TT];
            cs[wv][i] = (unsigned char)chars[w * TT + i % TT];
        }
    }
    __syncthreads();

    int word = sw[slotbase + n];
    int L = lens[word];
    int mL = L;                    // max over the wave's 16 words
    #pragma unroll
    for (int off = 8; off; off >>= 1) {
        int t2 = __shfl_xor(mL, off);
        mL = mL > t2 ? mL : t2;
    }
    mL = __builtin_amdgcn_readfirstlane(mL);

    const bf16x8* ap = (const bf16x8*)Wa;
    const bf16x8* bp = (const bf16x8*)hs[wv];
    short* hw = hs[wv];
    const unsigned char* cw = cs[wv] + n * TT;

    int pa0 = quad ^ x7;           // swizzled k-group, k 0..31
    int pa1 = (quad + 4) ^ x7;     // k 32..63

    float cst[TILES], hf[TILES];
    #pragma unroll
    for (int t = 0; t < TILES; ++t) { cst[t] = 0.0f; hf[t] = 0.0f; }

    #pragma unroll 1
    for (int s = 0; s < mL; ++s) {
        bool valid = s < L;
        int p = valid ? (d ? (L - 1 - s) : s) : 0;
        int v = cw[p];

        bf16x8 B0 = bp[n * 8 + pa0];     // h of step s-1, B-operand layout
        bf16x8 B1 = bp[n * 8 + pa1];

        // pass 1: MFMAs; acc init = bf16 G from LDS (char preactivation)
        f32x4 acc[TILES];
        #pragma unroll
        for (int t = 0; t < TILES; ++t) {
            int u = 4 * t + quad;
            s16x4 gv = *(const s16x4*)&Gl[v * GSTR + u * 4];
            f32x4 a;
            a[0] = bf2f(gv[0]); a[1] = bf2f(gv[1]);
            a[2] = bf2f(gv[2]); a[3] = bf2f(gv[3]);
            bf16x8 A0 = ap[(t * 16 + n) * 8 + pa0];
            bf16x8 A1 = ap[(t * 16 + n) * 8 + pa1];
            a = __builtin_amdgcn_mfma_f32_16x16x32_bf16(A0, B0, a, 0, 0, 0);
            a = __builtin_amdgcn_mfma_f32_16x16x32_bf16(A1, B1, a, 0, 0, 0);
            acc[t] = a;
        }
        // pass 2: lane-local gate math; h back to LDS in bf16
        #pragma unroll
        for (int t = 0; t < TILES; ++t) {
            int u = 4 * t + quad;
            float ig = fsig(acc[t][0]);
            float fg = fsig(acc[t][1]);
            float gg = ftanhf(acc[t][2]);
            float og = fsig(acc[t][3]);
            float cold = cst[t];
            float cn = fg * cold + ig * gg;
            float hn = og * ftanhf(cn);
            bool upd = valid && (u < HH);
            cst[t] = upd ? cn : cold;
            hf[t]  = upd ? hn : hf[t];
            if (upd) {
                int idx = n * 64 + (((u >> 3) ^ x7) << 3) + (u & 7);
                hw[idx] = f2bf(hn);      // skipped when invalid -> h frozen
            }
        }
    }

    float* orow = out + (size_t)word * (2 * HH) + d * HH;
    #pragma unroll
    for (int t = 0; t < TILES; ++t) {
        int u = 4 * t + quad;
        if (u < HH) orow[u] = hf[t];     // fp32 h
    }
}

extern "C" void kernel_launch(void* const* d_in, const int* in_sizes, int n_in,
                              void* d_out, int out_size, void* d_ws, size_t ws_size,
                              hipStream_t stream) {
    const int*   chars = (const int*)d_in[0];
    const int*   lens  = (const int*)d_in[1];
    const float* emb   = (const float*)d_in[2];
    const float* Wih_f = (const float*)d_in[3];
    const float* Whh_f = (const float*)d_in[4];
    const float* bih_f = (const float*)d_in[5];
    const float* bhh_f = (const float*)d_in[6];
    const float* Wih_b = (const float*)d_in[7];
    const float* Whh_b = (const float*)d_in[8];
    const float* bih_b = (const float*)d_in[9];
    const float* bhh_b = (const float*)d_in[10];
    float* out = (float*)d_out;

    short* Gimg = (short*)d_ws;    // 169600 B

    k_prep<<<(2 * GSH + 255) / 256, 256, 0, stream>>>(emb, Wih_f, bih_f, bhh_f,
                                                      Wih_b, bih_b, bhh_b, Gimg);
    k_lstm<<<256, 1024, 0, stream>>>(chars, lens, Gimg, Whh_f, Whh_b, out);
}

// Round 10
// 201.376 us; speedup vs baseline: 1.6149x; 1.6149x over previous
//
#include <hip/hip_runtime.h>

// CharBiLSTMEmbedder: N=32768 words, T=20, E=H=50, V=200, out [N,100] fp32.
//
// Round-9 (resubmit; R9 bench was a broker timeout, kernel never ran):
// fit the step loop in 64 VGPRs (the 1024-thr allocator targets 64 and ignored
// waves_per_eu/launch_bounds hints in R7/R8 -> acc[13] spilled, 496 MB FETCH).
//  - MFMA + gate math FUSED with a 2-tile software pipeline: live acc 52->8 regs.
//  - hf[13] eliminated: out written the step a word finishes (s==L-1) + L==0
//    zero epilogue.
//  - Keeps R8: 2 dispatches, in-block counting sort, magic-square wave
//    assignment, self-staged Wa, LDS-resident G (bf16), per-wave h (no barriers).

#define TT    20
#define HH    50
#define VV    200
#define TILES 13        // 13*16 = 208 rows >= 200
#define GSTR  212       // G LDS row stride in shorts (53 units * 4 gates)
#define GSH   (VV * GSTR)        // 42400 shorts per dir
#define WSH   (TILES * 16 * 64)  // 13312 shorts per dir
#define NW    32768

typedef __attribute__((ext_vector_type(8))) short bf16x8;
typedef __attribute__((ext_vector_type(4))) short s16x4;
typedef __attribute__((ext_vector_type(4))) float f32x4;

__device__ __forceinline__ float frcp(float x) { return __builtin_amdgcn_rcpf(x); }
__device__ __forceinline__ float fsig(float x) { return frcp(1.0f + __expf(-x)); }
__device__ __forceinline__ float ftanhf(float x) { return 1.0f - 2.0f * frcp(1.0f + __expf(2.0f * x)); }

__device__ __forceinline__ short f2bf(float x) {  // RNE fp32 -> bf16
    unsigned b = __builtin_bit_cast(unsigned, x);
    unsigned r = (b + 0x7FFFu + ((b >> 16) & 1u)) >> 16;
    return (short)r;
}
__device__ __forceinline__ float bf2f(short s) {
    return __builtin_bit_cast(float, ((unsigned)(unsigned short)s) << 16);
}

// Gimg[d][v*GSTR+u*4+g] = bf16(emb'[v].W_ih[g*50+u] + b_ih + b_hh)
__global__ void k_prep(const float* __restrict__ emb,
                       const float* __restrict__ Wih_f, const float* __restrict__ bih_f,
                       const float* __restrict__ bhh_f,
                       const float* __restrict__ Wih_b, const float* __restrict__ bih_b,
                       const float* __restrict__ bhh_b,
                       short* __restrict__ Gimg) {
    int idx = blockIdx.x * 256 + threadIdx.x;
    if (idx >= 2 * GSH) return;
    int d = idx / GSH;
    int rem = idx % GSH;
    int v = rem / GSTR;
    int u = (rem % GSTR) >> 2;
    int g = idx & 3;
    if (u >= HH) { Gimg[idx] = 0; return; }
    int r = g * HH + u;
    const float* Wih = d ? Wih_b : Wih_f;
    const float* bih = d ? bih_b : bih_f;
    const float* bhh = d ? bhh_b : bhh_f;
    float s = bih[r] + bhh[r];
    if (v != 0) {  // PAD row of emb is zero
        #pragma unroll 10
        for (int e = 0; e < HH; ++e) s = fmaf(emb[v * HH + e], Wih[r * HH + e], s);
    }
    Gimg[idx] = f2bf(s);
}

__global__ void __launch_bounds__(1024)
k_lstm(const int* __restrict__ chars, const int* __restrict__ lens,
       const short* __restrict__ Gimg,
       const float* __restrict__ Whh_f, const float* __restrict__ Whh_b,
       float* __restrict__ out) {
    __shared__ __align__(16) short Wa[WSH];        // 26624 B
    __shared__ __align__(16) short Gl[GSH];        // 84800 B
    __shared__ __align__(16) short hs[16][1024];   // 32768 B per-wave h
    __shared__ unsigned char cs[16][320];          //  5120 B per-wave chars
    __shared__ int sw[256];                        // sorted word ids
    __shared__ int hist[21], start[21];

    int gb   = blockIdx.x;         // 0..255
    int d    = gb & 1;
    int wb   = (gb >> 1) * 256;    // block's first word
    int tid  = threadIdx.x;        // 0..1023
    int lane = tid & 63;
    int wv   = __builtin_amdgcn_readfirstlane(tid >> 6);   // 0..15
    int quad = lane >> 4;
    int n    = lane & 15;
    int x7   = n & 7;

    // ---- stage Wa from Whh (bf16, MFMA A-layout, k-swizzled); coalesced ----
    {
        const float* Whh = d ? Whh_b : Whh_f;
        for (int e = tid; e < WSH; e += 1024) {
            int t = e >> 10, m = (e >> 6) & 15, k = e & 63;
            int u = 4 * t + (m >> 2), g = m & 3;
            float val = (k < HH && u < HH) ? Whh[(g * HH + u) * HH + k] : 0.0f;
            int ksw = (k & 7) | (((k >> 3) ^ (m & 7)) << 3);
            Wa[(e & ~63) + ksw] = f2bf(val);
        }
    }
    // ---- copy G image (coalesced int4) ----
    {
        const int4* src = (const int4*)(Gimg + d * GSH);
        int4* dst = (int4*)Gl;
        for (int i = tid; i < GSH / 8; i += 1024) dst[i] = src[i];
    }
    // ---- zero h buffers ----
    {
        int4 z = {0, 0, 0, 0};
        int4* hz = (int4*)&hs[0][0];
        for (int i = tid; i < 16 * 1024 / 8; i += 1024) hz[i] = z;
    }
    // ---- in-block counting sort of 256 word lengths (descending) ----
    if (tid < 21) hist[tid] = 0;
    __syncthreads();
    int Lw = 0;
    if (tid < 256) {
        Lw = lens[wb + tid];
        atomicAdd(&hist[Lw], 1);
    }
    __syncthreads();
    if (tid < 21) {   // start[L] = count of longer words (descending buckets)
        int s = 0;
        for (int l = tid + 1; l < 21; ++l) s += hist[l];
        start[tid] = s;
    }
    __syncthreads();
    if (tid < 256) {
        int pos = atomicAdd(&start[Lw], 1);
        sw[pos] = wb + tid;
    }
    __syncthreads();

    // magic-square group table: per-SIMD sums equal under both w%4 and w/4
    // wave->SIMD mappings (rows and cols of the 4x4 all sum to 30)
    const int gtab[16] = {0, 14, 13, 3, 11, 5, 6, 8, 7, 9, 10, 4, 12, 2, 1, 15};
    int slotbase = gtab[wv] * 16;

    {   // wave's 16 words x 20 chars -> u8 LDS
        for (int i = lane; i < 16 * TT; i += 64) {
            int w = sw[slotbase + i / TT];
            cs[wv][i] = (unsigned char)chars[w * TT + i % TT];
        }
    }
    __syncthreads();

    int word = sw[slotbase + n];
    int L = lens[word];
    int mL = L;                    // max over the wave's 16 words
    #pragma unroll
    for (int off = 8; off; off >>= 1) {
        int t2 = __shfl_xor(mL, off);
        mL = mL > t2 ? mL : t2;
    }
    mL = __builtin_amdgcn_readfirstlane(mL);

    const bf16x8* ap = (const bf16x8*)Wa;
    const bf16x8* bp = (const bf16x8*)hs[wv];
    short* hw = hs[wv];
    const unsigned char* cw = cs[wv] + n * TT;

    int pa0 = quad ^ x7;           // swizzled k-group, k 0..31
    int pa1 = (quad + 4) ^ x7;     // k 32..63

    float cst[TILES];
    #pragma unroll
    for (int t = 0; t < TILES; ++t) cst[t] = 0.0f;

    float* orow = out + (size_t)word * (2 * HH) + d * HH;

    #pragma unroll 1
    for (int s = 0; s < mL; ++s) {
        bool valid = s < L;
        int p = valid ? (d ? (L - 1 - s) : s) : 0;
        int v = cw[p];
        int grow = v * GSTR + quad * 4;  // Gl index of (v, u=quad)

        bf16x8 B0 = bp[n * 8 + pa0];     // h of step s-1, B-operand layout
        bf16x8 B1 = bp[n * 8 + pa1];

        // prologue: tile 0 MFMAs
        f32x4 aN;
        {
            s16x4 gv = *(const s16x4*)&Gl[grow];
            f32x4 a;
            a[0] = bf2f(gv[0]); a[1] = bf2f(gv[1]);
            a[2] = bf2f(gv[2]); a[3] = bf2f(gv[3]);
            bf16x8 A0 = ap[n * 8 + pa0];
            bf16x8 A1 = ap[n * 8 + pa1];
            a = __builtin_amdgcn_mfma_f32_16x16x32_bf16(A0, B0, a, 0, 0, 0);
            aN = __builtin_amdgcn_mfma_f32_16x16x32_bf16(A1, B1, a, 0, 0, 0);
        }
        // fused pipeline: issue tile t+1 MFMAs, then gate-math tile t
        #pragma unroll
        for (int t = 0; t < TILES; ++t) {
            f32x4 ac = aN;
            if (t + 1 < TILES) {
                s16x4 gv = *(const s16x4*)&Gl[grow + (t + 1) * 16];
                f32x4 a;
                a[0] = bf2f(gv[0]); a[1] = bf2f(gv[1]);
                a[2] = bf2f(gv[2]); a[3] = bf2f(gv[3]);
                bf16x8 A0 = ap[((t + 1) * 16 + n) * 8 + pa0];
                bf16x8 A1 = ap[((t + 1) * 16 + n) * 8 + pa1];
                a = __builtin_amdgcn_mfma_f32_16x16x32_bf16(A0, B0, a, 0, 0, 0);
                aN = __builtin_amdgcn_mfma_f32_16x16x32_bf16(A1, B1, a, 0, 0, 0);
            }
            int u = 4 * t + quad;
            float ig = fsig(ac[0]);
            float fg = fsig(ac[1]);
            float gg = ftanhf(ac[2]);
            float og = fsig(ac[3]);
            float cn = fg * cst[t] + ig * gg;
            float hn = og * ftanhf(cn);
            bool upd = valid && (u < HH);
            if (upd) {
                cst[t] = cn;
                int idx = n * 64 + (((u >> 3) ^ x7) << 3) + (u & 7);
                hw[idx] = f2bf(hn);            // frozen when invalid
                if (s == L - 1) orow[u] = hn;  // word finishes: fp32 out
            }
        }
    }

    // L==0 words never stored: h = 0
    if (L == 0) {
        #pragma unroll
        for (int t = 0; t < TILES; ++t) {
            int u = 4 * t + quad;
            if (u < HH) orow[u] = 0.0f;
        }
    }
}

extern "C" void kernel_launch(void* const* d_in, const int* in_sizes, int n_in,
                              void* d_out, int out_size, void* d_ws, size_t ws_size,
                              hipStream_t stream) {
    const int*   chars = (const int*)d_in[0];
    const int*   lens  = (const int*)d_in[1];
    const float* emb   = (const float*)d_in[2];
    const float* Wih_f = (const float*)d_in[3];
    const float* Whh_f = (const float*)d_in[4];
    const float* bih_f = (const float*)d_in[5];
    const float* bhh_f = (const float*)d_in[6];
    const float* Wih_b = (const float*)d_in[7];
    const float* Whh_b = (const float*)d_in[8];
    const float* bih_b = (const float*)d_in[9];
    const float* bhh_b = (const float*)d_in[10];
    float* out = (float*)d_out;

    short* Gimg = (short*)d_ws;    // 169600 B

    k_prep<<<(2 * GSH + 255) / 256, 256, 0, stream>>>(emb, Wih_f, bih_f, bhh_f,
                                                      Wih_b, bih_b, bhh_b, Gimg);
    k_lstm<<<256, 1024, 0, stream>>>(chars, lens, Gimg, Whh_f, Whh_b, out);
}

// Round 11
// 167.236 us; speedup vs baseline: 1.9445x; 1.2041x over previous
//
#include <hip/hip_runtime.h>

// CharBiLSTMEmbedder: N=32768 words, T=20, E=H=50, V=200, out [N,100] fp32.
//
// Round-11: escape the 1024-thr allocator trap (it targets 8 waves/EU, ignores
// the LDS block cap, and spills): 768-thr blocks (12 waves = 3/SIMD, VGPR cap
// 170) + the fused 2-tile pipeline (live set ~60 regs -> spill-free even if the
// heuristic over-targets).
//  - global descending counting sort restored (41.8K wave-steps vs 46K in-block):
//    k_prep(G+hist) -> k_scat(self-scan+scatter) -> k_lstm. LPT dispatch order.
//  - exp2 prescaling: gate rows scaled by log2e (i,f,o) / 2*log2e (g) in BOTH
//    G and Wa staging -> __expf's v_mul disappears; v_exp with free neg modifier.
//  - LDS 136.6 KB: Wa 26.6 + Gl 84.8 + hs 24.6 + cs 3.8.

#define TT    20
#define HH    50
#define VV    200
#define TILES 13        // 13*16 = 208 rows >= 200
#define GSTR  212       // G LDS row stride in shorts (53 units * 4 gates)
#define GSH   (VV * GSTR)        // 42400 shorts per dir
#define WSH   (TILES * 16 * 64)  // 13312 shorts per dir
#define NW    32768
#define NB_G  332       // ceil(2*GSH/256)
#define NB_H  128       // 128*256 = 32768 words
#define NBLK  342       // 2 dirs * ceil(2048 groups / 12 waves)

#define L2E      1.4426950408889634f
#define TWO_L2E  2.8853900817779268f

typedef __attribute__((ext_vector_type(8))) short bf16x8;
typedef __attribute__((ext_vector_type(4))) short s16x4;
typedef __attribute__((ext_vector_type(4))) float f32x4;

__device__ __forceinline__ float frcp(float x) { return __builtin_amdgcn_rcpf(x); }
__device__ __forceinline__ float fexp2(float x) { return __builtin_amdgcn_exp2f(x); }

__device__ __forceinline__ short f2bf(float x) {  // RNE fp32 -> bf16
    unsigned b = __builtin_bit_cast(unsigned, x);
    unsigned r = (b + 0x7FFFu + ((b >> 16) & 1u)) >> 16;
    return (short)r;
}
__device__ __forceinline__ float bf2f(short s) {
    return __builtin_bit_cast(float, ((unsigned)(unsigned short)s) << 16);
}

// [0,NB_G): Gimg[d][v*GSTR+u*4+g] = bf16(scale_g * (emb'[v].W_ih[g*50+u]+b_ih+b_hh))
// [NB_G,NB_G+NB_H): cnt[b][21] = length histogram
__global__ void k_prep(const float* __restrict__ emb,
                       const float* __restrict__ Wih_f, const float* __restrict__ bih_f,
                       const float* __restrict__ bhh_f,
                       const float* __restrict__ Wih_b, const float* __restrict__ bih_b,
                       const float* __restrict__ bhh_b,
                       const int* __restrict__ lens,
                       short* __restrict__ Gimg, int* __restrict__ cnt) {
    int blk = blockIdx.x;
    int tid = threadIdx.x;
    if (blk < NB_G) {
        int idx = blk * 256 + tid;
        if (idx >= 2 * GSH) return;
        int d = idx / GSH;
        int rem = idx % GSH;
        int v = rem / GSTR;
        int u = (rem % GSTR) >> 2;
        int g = idx & 3;
        if (u >= HH) { Gimg[idx] = 0; return; }
        int r = g * HH + u;
        const float* Wih = d ? Wih_b : Wih_f;
        const float* bih = d ? bih_b : bih_f;
        const float* bhh = d ? bhh_b : bhh_f;
        float s = bih[r] + bhh[r];
        if (v != 0) {  // PAD row of emb is zero
            #pragma unroll 10
            for (int e = 0; e < HH; ++e) s = fmaf(emb[v * HH + e], Wih[r * HH + e], s);
        }
        s *= (g == 2) ? TWO_L2E : L2E;   // exp2 prescale (tanh gate gets 2x)
        Gimg[idx] = f2bf(s);
    } else {
        int hb = blk - NB_G;             // 0..127
        __shared__ int hcnt[21];
        if (tid < 21) hcnt[tid] = 0;
        __syncthreads();
        atomicAdd(&hcnt[lens[hb * 256 + tid]], 1);
        __syncthreads();
        if (tid < 21) cnt[hb * 21 + tid] = hcnt[tid];
    }
}

// Self-scanning scatter: bucket-major perm, buckets L=20..0 (descending).
__global__ void k_scat(const int* __restrict__ lens, const int* __restrict__ cnt,
                       int* __restrict__ perm) {
    __shared__ int tots[21], before_s[21], cur[21];
    int b = blockIdx.x, t = threadIdx.x;
    if (t < 21) {
        int before = 0, tot = 0;
        for (int bb = 0; bb < NB_H; ++bb) {
            int c = cnt[bb * 21 + t];
            before += (bb < b) ? c : 0;
            tot += c;
        }
        tots[t] = tot;
        before_s[t] = before;
    }
    __syncthreads();
    if (t < 21) {
        int start = 0;
        for (int L = 20; L > t; --L) start += tots[L];
        cur[t] = start + before_s[t];
    }
    __syncthreads();
    int i = b * 256 + t;
    int pos = atomicAdd(&cur[lens[i]], 1);
    perm[pos] = i;
}

__global__ void __launch_bounds__(768, 3)
k_lstm(const int* __restrict__ chars, const int* __restrict__ lens,
       const int* __restrict__ perm, const short* __restrict__ Gimg,
       const float* __restrict__ Whh_f, const float* __restrict__ Whh_b,
       float* __restrict__ out) {
    __shared__ __align__(16) short Wa[WSH];        // 26624 B
    __shared__ __align__(16) short Gl[GSH];        // 84800 B
    __shared__ __align__(16) short hs[12][1024];   // 24576 B per-wave h
    __shared__ unsigned char cs[12][320];          //  3840 B per-wave chars

    int gb   = blockIdx.x;         // 0..341 (descending length: LPT)
    int d    = gb & 1;
    int grp  = gb >> 1;            // 0..170
    int tid  = threadIdx.x;        // 0..767
    int lane = tid & 63;
    int wv   = __builtin_amdgcn_readfirstlane(tid >> 6);   // 0..11
    int quad = lane >> 4;
    int n    = lane & 15;
    int x7   = n & 7;

    // ---- stage Wa from Whh (bf16, MFMA A-layout, k-swizzled, prescaled) ----
    {
        const float* Whh = d ? Whh_b : Whh_f;
        for (int e = tid; e < WSH; e += 768) {
            int t = e >> 10, m = (e >> 6) & 15, k = e & 63;
            int u = 4 * t + (m >> 2), g = m & 3;
            float val = (k < HH && u < HH) ? Whh[(g * HH + u) * HH + k] : 0.0f;
            val *= (g == 2) ? TWO_L2E : L2E;
            int ksw = (k & 7) | (((k >> 3) ^ (m & 7)) << 3);
            Wa[(e & ~63) + ksw] = f2bf(val);
        }
    }
    // ---- copy G image (coalesced int4) ----
    {
        const int4* src = (const int4*)(Gimg + d * GSH);
        int4* dst = (int4*)Gl;
        for (int i = tid; i < GSH / 8; i += 768) dst[i] = src[i];
    }
    // ---- zero h buffers ----
    {
        int4 z = {0, 0, 0, 0};
        int4* hz = (int4*)&hs[0][0];
        for (int i = tid; i < 12 * 1024 / 8; i += 768) hz[i] = z;
    }
    // group of 16 sorted slots per wave; clamp tail (dup work is benign:
    // same values written to same outputs)
    int g = grp * 12 + wv;
    if (g > 2047) g = 2047;
    int slotbase = g * 16;
    {   // wave's 16 words x 20 chars -> u8 LDS
        for (int i = lane; i < 16 * TT; i += 64) {
            int w = perm[slotbase + i / TT];
            cs[wv][i] = (unsigned char)chars[w * TT + i % TT];
        }
    }
    __syncthreads();

    int word = perm[slotbase + n];
    int L = lens[word];
    int mL = L;                    // max over the wave's 16 words
    #pragma unroll
    for (int off = 8; off; off >>= 1) {
        int t2 = __shfl_xor(mL, off);
        mL = mL > t2 ? mL : t2;
    }
    mL = __builtin_amdgcn_readfirstlane(mL);

    const bf16x8* ap = (const bf16x8*)Wa;
    const bf16x8* bp = (const bf16x8*)hs[wv];
    short* hw = hs[wv];
    const unsigned char* cw = cs[wv] + n * TT;

    int pa0 = quad ^ x7;           // swizzled k-group, k 0..31
    int pa1 = (quad + 4) ^ x7;     // k 32..63

    float cst[TILES];
    #pragma unroll
    for (int t = 0; t < TILES; ++t) cst[t] = 0.0f;

    float* orow = out + (size_t)word * (2 * HH) + d * HH;

    #pragma unroll 1
    for (int s = 0; s < mL; ++s) {
        bool valid = s < L;
        int p = valid ? (d ? (L - 1 - s) : s) : 0;
        int v = cw[p];
        int grow = v * GSTR + quad * 4;  // Gl index of (v, u=quad)

        bf16x8 B0 = bp[n * 8 + pa0];     // h of step s-1, B-operand layout
        bf16x8 B1 = bp[n * 8 + pa1];

        // prologue: tile 0 MFMAs
        f32x4 aN;
        {
            s16x4 gv = *(const s16x4*)&Gl[grow];
            f32x4 a;
            a[0] = bf2f(gv[0]); a[1] = bf2f(gv[1]);
            a[2] = bf2f(gv[2]); a[3] = bf2f(gv[3]);
            bf16x8 A0 = ap[n * 8 + pa0];
            bf16x8 A1 = ap[n * 8 + pa1];
            a = __builtin_amdgcn_mfma_f32_16x16x32_bf16(A0, B0, a, 0, 0, 0);
            aN = __builtin_amdgcn_mfma_f32_16x16x32_bf16(A1, B1, a, 0, 0, 0);
        }
        // fused pipeline: issue tile t+1 MFMAs, then gate-math tile t
        #pragma unroll
        for (int t = 0; t < TILES; ++t) {
            f32x4 ac = aN;
            if (t + 1 < TILES) {
                s16x4 gv = *(const s16x4*)&Gl[grow + (t + 1) * 16];
                f32x4 a;
                a[0] = bf2f(gv[0]); a[1] = bf2f(gv[1]);
                a[2] = bf2f(gv[2]); a[3] = bf2f(gv[3]);
                bf16x8 A0 = ap[((t + 1) * 16 + n) * 8 + pa0];
                bf16x8 A1 = ap[((t + 1) * 16 + n) * 8 + pa1];
                a = __builtin_amdgcn_mfma_f32_16x16x32_bf16(A0, B0, a, 0, 0, 0);
                aN = __builtin_amdgcn_mfma_f32_16x16x32_bf16(A1, B1, a, 0, 0, 0);
            }
            int u = 4 * t + quad;
            // prescaled gates: sigma(x) = rcp(1+exp2(-xs)); tanh via exp2(xs)
            float ig = frcp(1.0f + fexp2(-ac[0]));
            float fg = frcp(1.0f + fexp2(-ac[1]));
            float og = frcp(1.0f + fexp2(-ac[3]));
            float gg = fmaf(-2.0f, frcp(1.0f + fexp2(ac[2])), 1.0f);
            float cn = fg * cst[t] + ig * gg;
            float th = fmaf(-2.0f, frcp(1.0f + fexp2(TWO_L2E * cn)), 1.0f);
            float hn = og * th;
            bool upd = valid && (u < HH);
            if (upd) {
                cst[t] = cn;
                int idx = n * 64 + (((u >> 3) ^ x7) << 3) + (u & 7);
                hw[idx] = f2bf(hn);            // frozen when invalid
                if (s == L - 1) orow[u] = hn;  // word finishes: fp32 out
            }
        }
    }

    // L==0 words never stored: h = 0
    if (L == 0) {
        #pragma unroll
        for (int t = 0; t < TILES; ++t) {
            int u = 4 * t + quad;
            if (u < HH) orow[u] = 0.0f;
        }
    }
}

extern "C" void kernel_launch(void* const* d_in, const int* in_sizes, int n_in,
                              void* d_out, int out_size, void* d_ws, size_t ws_size,
                              hipStream_t stream) {
    const int*   chars = (const int*)d_in[0];
    const int*   lens  = (const int*)d_in[1];
    const float* emb   = (const float*)d_in[2];
    const float* Wih_f = (const float*)d_in[3];
    const float* Whh_f = (const float*)d_in[4];
    const float* bih_f = (const float*)d_in[5];
    const float* bhh_f = (const float*)d_in[6];
    const float* Wih_b = (const float*)d_in[7];
    const float* Whh_b = (const float*)d_in[8];
    const float* bih_b = (const float*)d_in[9];
    const float* bhh_b = (const float*)d_in[10];
    float* out = (float*)d_out;

    short* Gimg = (short*)d_ws;                 // 169600 B
    int*   cnt  = (int*)(Gimg + 2 * GSH);       //  10752 B
    int*   perm = cnt + NB_H * 21;              // 131072 B

    k_prep<<<NB_G + NB_H, 256, 0, stream>>>(emb, Wih_f, bih_f, bhh_f,
                                            Wih_b, bih_b, bhh_b, lens, Gimg, cnt);
    k_scat<<<NB_H, 256, 0, stream>>>(lens, cnt, perm);
    k_lstm<<<NBLK, 768, 0, stream>>>(chars, lens, perm, Gimg, Whh_f, Whh_b, out);
}

// Round 12
// 166.818 us; speedup vs baseline: 1.9494x; 1.0025x over previous
//
#include <hip/hip_runtime.h>

// CharBiLSTMEmbedder: N=32768 words, T=20, E=H=50, V=200, out [N,100] fp32.
//
// Round-12: A-operand (Whh) hoisted into VGPRs for the whole kernel.
// R11 analysis: kernel is makespan-bound by the L=20 blocks (20 steps x
// per-step-row wall λ); λ was inflated by 26 ds_read_b128/step of a
// STEP-INVARIANT matrix. Now: Af[26] (104 VGPRs) loaded once from a plain
// (unswizzled) global A-image; per-step LDS = 2 B-reads + 13 G-reads +
// 13 h-writes only. Wa leaves LDS (113 KB total). B keeps its swizzle
// (k-slot correspondence A-plain/B-swizzled verified: read phase pa0=quad^x7
// un-does the write swizzle -> k-group quad*8..).
// Keeps R11: 768 thr (3 waves/SIMD, no allocator trap), global descending
// sort + LPT, exp2 prescale, fused 2-tile pipeline, store-on-finish.

#define TT    20
#define HH    50
#define VV    200
#define TILES 13        // 13*16 = 208 rows >= 200
#define GSTR  212       // G LDS row stride in shorts (53 units * 4 gates)
#define GSH   (VV * GSTR)        // 42400 shorts per dir
#define WSH   (TILES * 16 * 64)  // 13312 shorts per dir
#define NW    32768
#define NB_G  332       // ceil(2*GSH/256)
#define NB_W  104       // 2*WSH/256 exact
#define NB_H  128       // 128*256 = 32768 words
#define NBLK  342       // 2 dirs * ceil(2048 groups / 12 waves)

#define L2E      1.4426950408889634f
#define TWO_L2E  2.8853900817779268f

typedef __attribute__((ext_vector_type(8))) short bf16x8;
typedef __attribute__((ext_vector_type(4))) short s16x4;
typedef __attribute__((ext_vector_type(4))) float f32x4;

__device__ __forceinline__ float frcp(float x) { return __builtin_amdgcn_rcpf(x); }
__device__ __forceinline__ float fexp2(float x) { return __builtin_amdgcn_exp2f(x); }

__device__ __forceinline__ short f2bf(float x) {  // RNE fp32 -> bf16
    unsigned b = __builtin_bit_cast(unsigned, x);
    unsigned r = (b + 0x7FFFu + ((b >> 16) & 1u)) >> 16;
    return (short)r;
}
__device__ __forceinline__ float bf2f(short s) {
    return __builtin_bit_cast(float, ((unsigned)(unsigned short)s) << 16);
}

// [0,NB_G): Gimg[d][v*GSTR+u*4+g] = bf16(scale_g*(emb'[v].W_ih[g*50+u]+b_ih+b_hh))
// [NB_G,+NB_W): Wimg = PLAIN A-operand image of Whh (bf16, prescaled, no swizzle)
// [NB_G+NB_W,+NB_H): cnt[b][21] = length histogram
__global__ void k_prep(const float* __restrict__ emb,
                       const float* __restrict__ Wih_f, const float* __restrict__ bih_f,
                       const float* __restrict__ bhh_f,
                       const float* __restrict__ Wih_b, const float* __restrict__ bih_b,
                       const float* __restrict__ bhh_b,
                       const float* __restrict__ Whh_f, const float* __restrict__ Whh_b,
                       const int* __restrict__ lens,
                       short* __restrict__ Gimg, short* __restrict__ Wimg,
                       int* __restrict__ cnt) {
    int blk = blockIdx.x;
    int tid = threadIdx.x;
    if (blk < NB_G) {
        int idx = blk * 256 + tid;
        if (idx >= 2 * GSH) return;
        int d = idx / GSH;
        int rem = idx % GSH;
        int v = rem / GSTR;
        int u = (rem % GSTR) >> 2;
        int g = idx & 3;
        if (u >= HH) { Gimg[idx] = 0; return; }
        int r = g * HH + u;
        const float* Wih = d ? Wih_b : Wih_f;
        const float* bih = d ? bih_b : bih_f;
        const float* bhh = d ? bhh_b : bhh_f;
        float s = bih[r] + bhh[r];
        if (v != 0) {  // PAD row of emb is zero
            #pragma unroll 10
            for (int e = 0; e < HH; ++e) s = fmaf(emb[v * HH + e], Wih[r * HH + e], s);
        }
        s *= (g == 2) ? TWO_L2E : L2E;   // exp2 prescale (tanh gate gets 2x)
        Gimg[idx] = f2bf(s);
    } else if (blk < NB_G + NB_W) {
        int idx = (blk - NB_G) * 256 + tid;   // 0..2*WSH
        int d = idx / WSH;
        int e = idx % WSH;
        int t = e >> 10, m = (e >> 6) & 15, k = e & 63;
        int u = 4 * t + (m >> 2), g = m & 3;
        const float* Whh = d ? Whh_b : Whh_f;
        float val = (k < HH && u < HH) ? Whh[(g * HH + u) * HH + k] : 0.0f;
        val *= (g == 2) ? TWO_L2E : L2E;
        Wimg[idx] = f2bf(val);               // plain layout: A lives in VGPRs now
    } else {
        int hb = blk - NB_G - NB_W;          // 0..127
        __shared__ int hcnt[21];
        if (tid < 21) hcnt[tid] = 0;
        __syncthreads();
        atomicAdd(&hcnt[lens[hb * 256 + tid]], 1);
        __syncthreads();
        if (tid < 21) cnt[hb * 21 + tid] = hcnt[tid];
    }
}

// Self-scanning scatter: bucket-major perm, buckets L=20..0 (descending).
__global__ void k_scat(const int* __restrict__ lens, const int* __restrict__ cnt,
                       int* __restrict__ perm) {
    __shared__ int tots[21], before_s[21], cur[21];
    int b = blockIdx.x, t = threadIdx.x;
    if (t < 21) {
        int before = 0, tot = 0;
        for (int bb = 0; bb < NB_H; ++bb) {
            int c = cnt[bb * 21 + t];
            before += (bb < b) ? c : 0;
            tot += c;
        }
        tots[t] = tot;
        before_s[t] = before;
    }
    __syncthreads();
    if (t < 21) {
        int start = 0;
        for (int L = 20; L > t; --L) start += tots[L];
        cur[t] = start + before_s[t];
    }
    __syncthreads();
    int i = b * 256 + t;
    int pos = atomicAdd(&cur[lens[i]], 1);
    perm[pos] = i;
}

__global__ void __launch_bounds__(768, 3)
k_lstm(const int* __restrict__ chars, const int* __restrict__ lens,
       const int* __restrict__ perm, const short* __restrict__ Gimg,
       const short* __restrict__ Wimg,
       float* __restrict__ out) {
    __shared__ __align__(16) short Gl[GSH];        // 84800 B
    __shared__ __align__(16) short hs[12][1024];   // 24576 B per-wave h
    __shared__ unsigned char cs[12][320];          //  3840 B per-wave chars

    int gb   = blockIdx.x;         // 0..341 (descending length: LPT)
    int d    = gb & 1;
    int grp  = gb >> 1;            // 0..170
    int tid  = threadIdx.x;        // 0..767
    int lane = tid & 63;
    int wv   = __builtin_amdgcn_readfirstlane(tid >> 6);   // 0..11
    int quad = lane >> 4;
    int n    = lane & 15;
    int x7   = n & 7;

    // ---- copy G image (coalesced int4) ----
    {
        const int4* src = (const int4*)(Gimg + d * GSH);
        int4* dst = (int4*)Gl;
        for (int i = tid; i < GSH / 8; i += 768) dst[i] = src[i];
    }
    // ---- zero h buffers ----
    {
        int4 z = {0, 0, 0, 0};
        int4* hz = (int4*)&hs[0][0];
        for (int i = tid; i < 12 * 1024 / 8; i += 768) hz[i] = z;
    }
    // group of 16 sorted slots per wave; clamp tail (dup work benign)
    int g = grp * 12 + wv;
    if (g > 2047) g = 2047;
    int slotbase = g * 16;
    {   // wave's 16 words x 20 chars -> u8 LDS
        for (int i = lane; i < 16 * TT; i += 64) {
            int w = perm[slotbase + i / TT];
            cs[wv][i] = (unsigned char)chars[w * TT + i % TT];
        }
    }

    // ---- A-operand fragments: loaded ONCE into VGPRs (step-invariant) ----
    const bf16x8* wp = (const bf16x8*)(Wimg + d * WSH);
    bf16x8 Af0[TILES], Af1[TILES];
    #pragma unroll
    for (int t = 0; t < TILES; ++t) {
        Af0[t] = wp[(t * 16 + n) * 8 + quad];       // k-group quad   (k 0..31)
        Af1[t] = wp[(t * 16 + n) * 8 + 4 + quad];   // k-group quad+4 (k 32..63)
    }
    __syncthreads();

    int word = perm[slotbase + n];
    int L = lens[word];
    int mL = L;                    // max over the wave's 16 words
    #pragma unroll
    for (int off = 8; off; off >>= 1) {
        int t2 = __shfl_xor(mL, off);
        mL = mL > t2 ? mL : t2;
    }
    mL = __builtin_amdgcn_readfirstlane(mL);

    const bf16x8* bp = (const bf16x8*)hs[wv];
    short* hw = hs[wv];
    const unsigned char* cw = cs[wv] + n * TT;

    int pa0 = quad ^ x7;           // swizzled k-group, k 0..31
    int pa1 = (quad + 4) ^ x7;     // k 32..63

    float cst[TILES];
    #pragma unroll
    for (int t = 0; t < TILES; ++t) cst[t] = 0.0f;

    float* orow = out + (size_t)word * (2 * HH) + d * HH;

    #pragma unroll 1
    for (int s = 0; s < mL; ++s) {
        bool valid = s < L;
        int p = valid ? (d ? (L - 1 - s) : s) : 0;
        int v = cw[p];
        int grow = v * GSTR + quad * 4;  // Gl index of (v, u=quad)

        bf16x8 B0 = bp[n * 8 + pa0];     // h of step s-1, B-operand layout
        bf16x8 B1 = bp[n * 8 + pa1];

        // prologue: tile 0 MFMAs
        f32x4 aN;
        {
            s16x4 gv = *(const s16x4*)&Gl[grow];
            f32x4 a;
            a[0] = bf2f(gv[0]); a[1] = bf2f(gv[1]);
            a[2] = bf2f(gv[2]); a[3] = bf2f(gv[3]);
            a = __builtin_amdgcn_mfma_f32_16x16x32_bf16(Af0[0], B0, a, 0, 0, 0);
            aN = __builtin_amdgcn_mfma_f32_16x16x32_bf16(Af1[0], B1, a, 0, 0, 0);
        }
        // fused pipeline: issue tile t+1 MFMAs, then gate-math tile t
        #pragma unroll
        for (int t = 0; t < TILES; ++t) {
            f32x4 ac = aN;
            if (t + 1 < TILES) {
                s16x4 gv = *(const s16x4*)&Gl[grow + (t + 1) * 16];
                f32x4 a;
                a[0] = bf2f(gv[0]); a[1] = bf2f(gv[1]);
                a[2] = bf2f(gv[2]); a[3] = bf2f(gv[3]);
                a = __builtin_amdgcn_mfma_f32_16x16x32_bf16(Af0[t + 1], B0, a, 0, 0, 0);
                aN = __builtin_amdgcn_mfma_f32_16x16x32_bf16(Af1[t + 1], B1, a, 0, 0, 0);
            }
            int u = 4 * t + quad;
            // prescaled gates: sigma(x) = rcp(1+exp2(-xs)); tanh via exp2
            float ig = frcp(1.0f + fexp2(-ac[0]));
            float fg = frcp(1.0f + fexp2(-ac[1]));
            float og = frcp(1.0f + fexp2(-ac[3]));
            float gg = fmaf(-2.0f, frcp(1.0f + fexp2(ac[2])), 1.0f);
            float cn = fg * cst[t] + ig * gg;
            float th = fmaf(-2.0f, frcp(1.0f + fexp2(TWO_L2E * cn)), 1.0f);
            float hn = og * th;
            bool upd = valid && (u < HH);
            if (upd) {
                cst[t] = cn;
                int idx = n * 64 + (((u >> 3) ^ x7) << 3) + (u & 7);
                hw[idx] = f2bf(hn);            // frozen when invalid
                if (s == L - 1) orow[u] = hn;  // word finishes: fp32 out
            }
        }
    }

    // L==0 words never stored: h = 0
    if (L == 0) {
        #pragma unroll
        for (int t = 0; t < TILES; ++t) {
            int u = 4 * t + quad;
            if (u < HH) orow[u] = 0.0f;
        }
    }
}

extern "C" void kernel_launch(void* const* d_in, const int* in_sizes, int n_in,
                              void* d_out, int out_size, void* d_ws, size_t ws_size,
                              hipStream_t stream) {
    const int*   chars = (const int*)d_in[0];
    const int*   lens  = (const int*)d_in[1];
    const float* emb   = (const float*)d_in[2];
    const float* Wih_f = (const float*)d_in[3];
    const float* Whh_f = (const float*)d_in[4];
    const float* bih_f = (const float*)d_in[5];
    const float* bhh_f = (const float*)d_in[6];
    const float* Wih_b = (const float*)d_in[7];
    const float* Whh_b = (const float*)d_in[8];
    const float* bih_b = (const float*)d_in[9];
    const float* bhh_b = (const float*)d_in[10];
    float* out = (float*)d_out;

    short* Gimg = (short*)d_ws;                 // 169600 B
    short* Wimg = Gimg + 2 * GSH;               //  53248 B
    int*   cnt  = (int*)(Wimg + 2 * WSH);       //  10752 B
    int*   perm = cnt + NB_H * 21;              // 131072 B

    k_prep<<<NB_G + NB_W + NB_H, 256, 0, stream>>>(emb, Wih_f, bih_f, bhh_f,
                                                   Wih_b, bih_b, bhh_b,
                                                   Whh_f, Whh_b, lens,
                                                   Gimg, Wimg, cnt);
    k_scat<<<NB_H, 256, 0, stream>>>(lens, cnt, perm);
    k_lstm<<<NBLK, 768, 0, stream>>>(chars, lens, perm, Gimg, Wimg, out);
}